// Round 4
// baseline (368.122 us; speedup 1.0000x reference)
//
#include <hip/hip_runtime.h>

// Single-head causal attention, B=512, T=256, C=384, HS=64.
// Primary path (needs ~50.5 MB d_ws): 3 kernels.
//   prep_wt:  pack Wq|Wk|Wv -> bf16 W^T [192][384].
//   qkv_proj: x@W -> Q(scaled)/K/V^T bf16 in d_ws; K h-XOR-swizzled, V^T
//             tok-XOR-swizzled IN GLOBAL so attn stages linearly via
//             global_load_lds and reads conflict-free.
//   attn:     one block per batch (512 thr / 8 waves, 74 KB LDS -> 2 blk/CU);
//             flash attention per wave over Q-tile pair {w, 15-w} (9 steps each).
// Fallback path (small d_ws): round-2 fused kernel (validated, ~156 us).

typedef float f32x4 __attribute__((ext_vector_type(4)));
typedef __bf16 bf16x8 __attribute__((ext_vector_type(8)));
typedef short s16x8 __attribute__((ext_vector_type(8)));

constexpr int T_ = 256;
constexpr int C_ = 384;
constexpr int HS_ = 64;
constexpr int QKVE = 512 * 256 * 64; // elems per tensor (8388608)

__device__ __forceinline__ short f2bs(float v) {
  __bf16 b = (__bf16)v;
  return __builtin_bit_cast(short, b);
}

__device__ __forceinline__ f32x4 mfma16(bf16x8 a, bf16x8 b, f32x4 c) {
  return __builtin_amdgcn_mfma_f32_16x16x32_bf16(a, b, c, 0, 0, 0);
}

// async global->LDS, 16B per lane. dst must be wave-uniform; src is per-lane.
__device__ __forceinline__ void gl_lds16(const short* g, short* l) {
  __builtin_amdgcn_global_load_lds((const __attribute__((address_space(1))) void*)g,
                                   (__attribute__((address_space(3))) void*)l,
                                   16, 0, 0);
}

// W^T pack: wt[n][k] = W_{n/64}[k][n%64] as bf16, n in [0,192), k in [0,384)
__global__ void prep_wt_kernel(const float* __restrict__ Wq,
                               const float* __restrict__ Wk,
                               const float* __restrict__ Wv,
                               short* __restrict__ wt) {
  int idx = blockIdx.x * 256 + threadIdx.x;
  if (idx >= 192 * 384) return;
  int n = idx / 384;
  int k = idx - n * 384;
  const float* W = (n < 64) ? Wq : (n < 128) ? Wk : Wv;
  int h = n & 63;
  wt[idx] = f2bs(W[k * 64 + h]);
}

// ---------------- Kernel 1: QKV projection ----------------
// 1024 blocks x 256 threads. Block = 128 token-rows of one batch; wave = 2 M-tiles.
__global__ __launch_bounds__(256, 3) void qkv_proj(const float* __restrict__ x,
                                                   const short* __restrict__ wt,
                                                   short* __restrict__ ws) {
  // wt tile for one K-step, chunk-major [lg][n][8] -> conflict-free b128 reads.
  __shared__ __align__(16) short wtile[2][4 * 192 * 8]; // 2 x 12 KB
  __shared__ __align__(16) short vbuf[128][65];         // 16.6 KB, V transpose buffer

  short* qg = ws;
  short* kg = ws + QKVE;
  short* vtg = ws + 2 * QKVE;

  const int blk = blockIdx.x;
  const int b = blk >> 1;
  const int rowbase = (blk & 1) * 128;
  const int tid = threadIdx.x;
  const int w = tid >> 6;
  const int lane = tid & 63;
  const int lr = tid & 15;
  const int lg = lane >> 4;

  const float* xb = x + (size_t)b * (T_ * C_);

  // stage wt tile for K-step ks into wtile[buf] (3 issues per wave).
  auto stage = [&](int buf, int ks) {
#pragma unroll
    for (int i = 0; i < 3; ++i) {
      int c = i * 256 + w * 64 + lane; // chunk 0..767 = lgc*192 + n
      int n = c % 192;
      int lgc = c / 192;
      const short* src = wt + n * 384 + ks * 32 + lgc * 8;
      short* dst = &wtile[buf][(i * 256 + w * 64) * 8]; // wave-uniform base
      gl_lds16(src, dst);
    }
  };

  f32x4 xf[2][2], xn[2][2];
  auto loadx = [&](f32x4 dst[2][2], int ks) {
#pragma unroll
    for (int m = 0; m < 2; ++m) {
      int row = rowbase + (2 * w + m) * 16 + lr;
      const f32x4* p = reinterpret_cast<const f32x4*>(xb + (size_t)row * C_ + ks * 32 + lg * 8);
      dst[m][0] = p[0];
      dst[m][1] = p[1];
    }
  };

  f32x4 acc[2][12];
#pragma unroll
  for (int m = 0; m < 2; ++m)
#pragma unroll
    for (int nt = 0; nt < 12; ++nt) acc[m][nt] = f32x4{0.f, 0.f, 0.f, 0.f};

  stage(0, 0);
  loadx(xf, 0);
  __syncthreads(); // drains vmcnt(0): wtile[0] + xf ready

  for (int ks = 0; ks < 12; ++ks) {
    const int cur = ks & 1;
    if (ks < 11) {
      stage(cur ^ 1, ks + 1);
      loadx(xn, ks + 1);
    }
    bf16x8 a[2];
#pragma unroll
    for (int m = 0; m < 2; ++m) {
      bf16x8 t;
      t[0] = (__bf16)xf[m][0][0]; t[1] = (__bf16)xf[m][0][1];
      t[2] = (__bf16)xf[m][0][2]; t[3] = (__bf16)xf[m][0][3];
      t[4] = (__bf16)xf[m][1][0]; t[5] = (__bf16)xf[m][1][1];
      t[6] = (__bf16)xf[m][1][2]; t[7] = (__bf16)xf[m][1][3];
      a[m] = t;
    }
#pragma unroll
    for (int nt = 0; nt < 12; ++nt) {
      bf16x8 bw = *reinterpret_cast<const bf16x8*>(&wtile[cur][(lg * 192 + nt * 16 + lr) * 8]);
      acc[0][nt] = mfma16(a[0], bw, acc[0][nt]);
      acc[1][nt] = mfma16(a[1], bw, acc[1][nt]);
    }
    __syncthreads(); // next tile staged + this tile's readers done
    if (ks < 11) {
#pragma unroll
      for (int m = 0; m < 2; ++m) {
        xf[m][0] = xn[m][0];
        xf[m][1] = xn[m][1];
      }
    }
  }

  // Stores. C-frag: col = lr (h within 16), row = lg*4 + j.
  const float QSCALE = 0.125f * 1.44269504f; // HS^-0.5 * log2(e)
#pragma unroll
  for (int nt = 0; nt < 12; ++nt) {
    const int which = nt >> 2;
    const int hb = (nt & 3) * 16 + lr;
#pragma unroll
    for (int m = 0; m < 2; ++m) {
#pragma unroll
      for (int j = 0; j < 4; ++j) {
        int t = rowbase + (2 * w + m) * 16 + lg * 4 + j; // token within batch
        float v = acc[m][nt][j];
        if (which == 0) {
          qg[(size_t)b * 16384 + t * 64 + hb] = f2bs(v * QSCALE);
        } else if (which == 1) {
          kg[(size_t)b * 16384 + t * 64 + (hb ^ ((t & 7) << 3))] = f2bs(v);
        } else {
          vbuf[t - rowbase][hb] = f2bs(v);
        }
      }
    }
  }
  __syncthreads();

  // V transpose repack: 1024 16B-chunks (h, 8-token group), 4 per thread.
#pragma unroll
  for (int r = 0; r < 4; ++r) {
    int c = r * 256 + tid; // 0..1023
    int h = c >> 4;        // 0..63
    int i = c & 15;        // 8-token chunk within the 128 rows
    s16x8 tv;
#pragma unroll
    for (int j = 0; j < 8; ++j) tv[j] = vbuf[i * 8 + j][h];
    int tokbase = (rowbase + i * 8) ^ ((h & 7) << 3); // swizzled global layout
    *reinterpret_cast<s16x8*>(vtg + (size_t)b * 16384 + h * 256 + tokbase) = tv;
  }
}

// ---------------- Kernel 2: causal flash attention ----------------
// 512 blocks (one per batch) x 512 threads (8 waves); 74 KB LDS -> 2 blocks/CU.
__global__ __launch_bounds__(512, 4) void attn(const short* __restrict__ ws,
                                               float* __restrict__ out) {
  __shared__ __align__(16) short KS[256 * 64];   // 32 KB, swizzled (from global)
  __shared__ __align__(16) short VT[64 * 256];   // 32 KB, V^T swizzled (from global)
  __shared__ __align__(16) short PB[8][16 * 40]; // 10 KB, per-wave P, pad 40

  const short* qg = ws;
  const short* kg = ws + QKVE;
  const short* vtg = ws + 2 * QKVE;

  const int b = blockIdx.x;
  const int tid = threadIdx.x;
  const int w = tid >> 6;
  const int lane = tid & 63;
  const int lr = tid & 15;
  const int lg = lane >> 4;

  // Bulk-stage K and V^T (32 KB each): 4 chunks of 1 KB per wave per tensor.
#pragma unroll
  for (int i = 0; i < 4; ++i) {
    int ch = w * 4 + i; // 0..31
    gl_lds16(kg + (size_t)b * 16384 + ch * 512 + lane * 8, &KS[ch * 512]);
    gl_lds16(vtg + (size_t)b * 16384 + ch * 512 + lane * 8, &VT[ch * 512]);
  }
  __syncthreads(); // drains vmcnt(0)

  for (int pass = 0; pass < 2; ++pass) {
    const int t = pass ? (15 - w) : w;
    // Q fragments straight from global (L2/L3-resident bf16).
    const short* qrow = qg + (size_t)b * 16384 + (t * 16 + lr) * 64;
    bf16x8 aq0 = *reinterpret_cast<const bf16x8*>(qrow + lg * 8);
    bf16x8 aq1 = *reinterpret_cast<const bf16x8*>(qrow + 32 + lg * 8);

    f32x4 o[4];
    float mrun[4], lrun[4];
#pragma unroll
    for (int nt = 0; nt < 4; ++nt) o[nt] = f32x4{0.f, 0.f, 0.f, 0.f};
#pragma unroll
    for (int j = 0; j < 4; ++j) { mrun[j] = -1e30f; lrun[j] = 0.f; }

    const int nkt = (t >> 1) + 1;
    for (int kt = 0; kt < nkt; ++kt) {
      f32x4 s0 = f32x4{0.f, 0.f, 0.f, 0.f};
      f32x4 s1 = f32x4{0.f, 0.f, 0.f, 0.f};
      {
        int kr0 = kt * 32 + lr;
        int kr1 = kr0 + 16;
        bf16x8 b00 = *reinterpret_cast<const bf16x8*>(&KS[kr0 * 64 + ((lg * 8) ^ ((kr0 & 7) << 3))]);
        bf16x8 b01 = *reinterpret_cast<const bf16x8*>(&KS[kr0 * 64 + ((32 + lg * 8) ^ ((kr0 & 7) << 3))]);
        bf16x8 b10 = *reinterpret_cast<const bf16x8*>(&KS[kr1 * 64 + ((lg * 8) ^ ((kr1 & 7) << 3))]);
        bf16x8 b11 = *reinterpret_cast<const bf16x8*>(&KS[kr1 * 64 + ((32 + lg * 8) ^ ((kr1 & 7) << 3))]);
        s0 = mfma16(aq0, b00, s0);
        s0 = mfma16(aq1, b01, s0);
        s1 = mfma16(aq0, b10, s1);
        s1 = mfma16(aq1, b11, s1);
      }

      if (kt == nkt - 1) { // causal mask on the straddling tile
#pragma unroll
        for (int j = 0; j < 4; ++j) {
          int row = t * 16 + lg * 4 + j;
          if (kt * 32 + lr > row)      s0[j] = -1e30f;
          if (kt * 32 + 16 + lr > row) s1[j] = -1e30f;
        }
      }

      // Online softmax in exp2 domain (row r: 16 lanes of group r/4, elem j=r%4).
      float alpha[4];
#pragma unroll
      for (int j = 0; j < 4; ++j) {
        float mx = fmaxf(s0[j], s1[j]);
        mx = fmaxf(mx, __shfl_xor(mx, 1));
        mx = fmaxf(mx, __shfl_xor(mx, 2));
        mx = fmaxf(mx, __shfl_xor(mx, 4));
        mx = fmaxf(mx, __shfl_xor(mx, 8));
        float mnew = fmaxf(mrun[j], mx);
        float al = exp2f(mrun[j] - mnew);
        mrun[j] = mnew;
        alpha[j] = al;
        float e0 = exp2f(s0[j] - mnew);
        float e1 = exp2f(s1[j] - mnew);
        float rs = e0 + e1;
        rs += __shfl_xor(rs, 1);
        rs += __shfl_xor(rs, 2);
        rs += __shfl_xor(rs, 4);
        rs += __shfl_xor(rs, 8);
        lrun[j] = lrun[j] * al + rs;
        int prow = lg * 4 + j;
        PB[w][prow * 40 + lr] = f2bs(e0);
        PB[w][prow * 40 + 16 + lr] = f2bs(e1);
      }

#pragma unroll
      for (int nt = 0; nt < 4; ++nt) {
        o[nt][0] *= alpha[0];
        o[nt][1] *= alpha[1];
        o[nt][2] *= alpha[2];
        o[nt][3] *= alpha[3];
      }
      bf16x8 ap = *reinterpret_cast<const bf16x8*>(&PB[w][lr * 40 + lg * 8]);
#pragma unroll
      for (int nt = 0; nt < 4; ++nt) {
        int h = nt * 16 + lr;
        bf16x8 bv = *reinterpret_cast<const bf16x8*>(&VT[h * 256 + ((kt * 32 + lg * 8) ^ ((h & 7) << 3))]);
        o[nt] = mfma16(ap, bv, o[nt]);
      }
    }

    float inv[4];
#pragma unroll
    for (int j = 0; j < 4; ++j) inv[j] = 1.0f / lrun[j];
    float* ob = out + ((size_t)b * T_ + t * 16 + lg * 4) * HS_;
#pragma unroll
    for (int nt = 0; nt < 4; ++nt)
#pragma unroll
      for (int j = 0; j < 4; ++j)
        ob[j * HS_ + nt * 16 + lr] = o[nt][j] * inv[j];
  }
}

// ---------------- Fallback: round-2 fused kernel (validated) ----------------
__device__ __forceinline__ int qswz(int row, int h) {
  return row * 64 + (h ^ ((row & 7) << 3));
}
__device__ __forceinline__ int vswz(int h, int tok) {
  return h * 256 + (tok ^ ((h & 7) << 3));
}

__global__ __launch_bounds__(512, 1) void fused_head(const float* __restrict__ x,
                                                     const short* __restrict__ wt,
                                                     float* __restrict__ out) {
  __shared__ __align__(16) short QS[256 * 64];
  __shared__ __align__(16) short KS[256 * 64];
  __shared__ __align__(16) short VT[64 * 256];
  __shared__ __align__(16) short PB[8][16 * 40];

  const int b = blockIdx.x;
  const int tid = threadIdx.x;
  const int w = tid >> 6;
  const int lr = tid & 15;
  const int lg = (tid & 63) >> 4;

  const float* xb = x + (size_t)b * (T_ * C_);

  f32x4 acc[2][12];
#pragma unroll
  for (int m = 0; m < 2; ++m)
#pragma unroll
    for (int nt = 0; nt < 12; ++nt) acc[m][nt] = f32x4{0.f, 0.f, 0.f, 0.f};

#pragma unroll
  for (int ks = 0; ks < 12; ++ks) {
    bf16x8 a[2];
#pragma unroll
    for (int m = 0; m < 2; ++m) {
      int row = (2 * w + m) * 16 + lr;
      const f32x4* p = reinterpret_cast<const f32x4*>(xb + row * C_ + ks * 32 + lg * 8);
      f32x4 f0 = p[0];
      f32x4 f1 = p[1];
      bf16x8 t;
      t[0] = (__bf16)f0[0]; t[1] = (__bf16)f0[1]; t[2] = (__bf16)f0[2]; t[3] = (__bf16)f0[3];
      t[4] = (__bf16)f1[0]; t[5] = (__bf16)f1[1]; t[6] = (__bf16)f1[2]; t[7] = (__bf16)f1[3];
      a[m] = t;
    }
#pragma unroll
    for (int nt = 0; nt < 12; ++nt) {
      bf16x8 bw = *reinterpret_cast<const bf16x8*>(wt + (nt * 16 + lr) * 384 + ks * 32 + lg * 8);
      acc[0][nt] = mfma16(a[0], bw, acc[0][nt]);
      acc[1][nt] = mfma16(a[1], bw, acc[1][nt]);
    }
  }

  const float QSCALE = 0.125f * 1.44269504f;
#pragma unroll
  for (int nt = 0; nt < 12; ++nt) {
    const int which = nt >> 2;
    const int hb = (nt & 3) * 16 + lr;
#pragma unroll
    for (int m = 0; m < 2; ++m) {
      const int rbase = (2 * w + m) * 16 + lg * 4;
#pragma unroll
      for (int j = 0; j < 4; ++j) {
        int row = rbase + j;
        float v = acc[m][nt][j];
        if (which == 0)      QS[qswz(row, hb)] = f2bs(v * QSCALE);
        else if (which == 1) KS[qswz(row, hb)] = f2bs(v);
        else                 VT[vswz(hb, row)] = f2bs(v);
      }
    }
  }

  __syncthreads();

  for (int pass = 0; pass < 2; ++pass) {
    const int t = pass ? (15 - w) : w;
    const int qrow = t * 16 + lr;
    bf16x8 aq0 = *reinterpret_cast<const bf16x8*>(&QS[qswz(qrow, lg * 8)]);
    bf16x8 aq1 = *reinterpret_cast<const bf16x8*>(&QS[qswz(qrow, 32 + lg * 8)]);

    f32x4 o[4];
    float mrun[4], lrun[4];
#pragma unroll
    for (int nt = 0; nt < 4; ++nt) o[nt] = f32x4{0.f, 0.f, 0.f, 0.f};
#pragma unroll
    for (int j = 0; j < 4; ++j) { mrun[j] = -1e30f; lrun[j] = 0.f; }

    const int nkt = (t >> 1) + 1;
    for (int kt = 0; kt < nkt; ++kt) {
      f32x4 s0 = f32x4{0.f, 0.f, 0.f, 0.f};
      f32x4 s1 = f32x4{0.f, 0.f, 0.f, 0.f};
      {
        int kr0 = kt * 32 + lr;
        int kr1 = kr0 + 16;
        bf16x8 b00 = *reinterpret_cast<const bf16x8*>(&KS[qswz(kr0, lg * 8)]);
        bf16x8 b01 = *reinterpret_cast<const bf16x8*>(&KS[qswz(kr0, 32 + lg * 8)]);
        bf16x8 b10 = *reinterpret_cast<const bf16x8*>(&KS[qswz(kr1, lg * 8)]);
        bf16x8 b11 = *reinterpret_cast<const bf16x8*>(&KS[qswz(kr1, 32 + lg * 8)]);
        s0 = mfma16(aq0, b00, s0);
        s0 = mfma16(aq1, b01, s0);
        s1 = mfma16(aq0, b10, s1);
        s1 = mfma16(aq1, b11, s1);
      }

      if (kt == nkt - 1) {
#pragma unroll
        for (int j = 0; j < 4; ++j) {
          int row = t * 16 + lg * 4 + j;
          if (kt * 32 + lr > row)      s0[j] = -1e30f;
          if (kt * 32 + 16 + lr > row) s1[j] = -1e30f;
        }
      }

      float alpha[4];
#pragma unroll
      for (int j = 0; j < 4; ++j) {
        float mx = fmaxf(s0[j], s1[j]);
        mx = fmaxf(mx, __shfl_xor(mx, 1));
        mx = fmaxf(mx, __shfl_xor(mx, 2));
        mx = fmaxf(mx, __shfl_xor(mx, 4));
        mx = fmaxf(mx, __shfl_xor(mx, 8));
        float mnew = fmaxf(mrun[j], mx);
        float al = exp2f(mrun[j] - mnew);
        mrun[j] = mnew;
        alpha[j] = al;
        float e0 = exp2f(s0[j] - mnew);
        float e1 = exp2f(s1[j] - mnew);
        float rs = e0 + e1;
        rs += __shfl_xor(rs, 1);
        rs += __shfl_xor(rs, 2);
        rs += __shfl_xor(rs, 4);
        rs += __shfl_xor(rs, 8);
        lrun[j] = lrun[j] * al + rs;
        int prow = lg * 4 + j;
        PB[w][prow * 40 + lr] = f2bs(e0);
        PB[w][prow * 40 + 16 + lr] = f2bs(e1);
      }

#pragma unroll
      for (int nt = 0; nt < 4; ++nt) {
        o[nt][0] *= alpha[0];
        o[nt][1] *= alpha[1];
        o[nt][2] *= alpha[2];
        o[nt][3] *= alpha[3];
      }
      bf16x8 ap = *reinterpret_cast<const bf16x8*>(&PB[w][lr * 40 + lg * 8]);
#pragma unroll
      for (int nt = 0; nt < 4; ++nt) {
        int h = nt * 16 + lr;
        bf16x8 bv = *reinterpret_cast<const bf16x8*>(&VT[vswz(h, kt * 32 + lg * 8)]);
        o[nt] = mfma16(ap, bv, o[nt]);
      }
    }

    float inv[4];
#pragma unroll
    for (int j = 0; j < 4; ++j) inv[j] = 1.0f / lrun[j];
    float* ob = out + ((size_t)b * T_ + t * 16 + lg * 4) * HS_;
#pragma unroll
    for (int nt = 0; nt < 4; ++nt)
#pragma unroll
      for (int j = 0; j < 4; ++j)
        ob[j * HS_ + nt * 16 + lr] = o[nt][j] * inv[j];
  }
}

extern "C" void kernel_launch(void* const* d_in, const int* in_sizes, int n_in,
                              void* d_out, int out_size, void* d_ws, size_t ws_size,
                              hipStream_t stream) {
  const float* x = (const float*)d_in[0];
  const float* Wq = (const float*)d_in[1];
  const float* Wk = (const float*)d_in[2];
  const float* Wv = (const float*)d_in[3];
  float* out = (float*)d_out;
  short* ws = (short*)d_ws;

  const size_t need = ((size_t)3 * QKVE + 192 * 384) * sizeof(short); // ~50.5 MB

  if (ws_size >= need) {
    short* wt = ws + 3 * QKVE;
    prep_wt_kernel<<<288, 256, 0, stream>>>(Wq, Wk, Wv, wt);
    qkv_proj<<<1024, 256, 0, stream>>>(x, wt, ws);
    attn<<<512, 512, 0, stream>>>(ws, out);
  } else {
    short* wt = ws; // needs only 147456 B
    prep_wt_kernel<<<288, 256, 0, stream>>>(Wq, Wk, Wv, wt);
    fused_head<<<512, 512, 0, stream>>>(x, wt, out);
  }
}